// Round 5
// baseline (1323.683 us; speedup 1.0000x reference)
//
#include <hip/hip_runtime.h>
#include <cstdint>

#define NN 20000     // nodes
#define NE 640000    // edges
#define NB 128       // basis
#define NG 64        // gaussians
#define NH 256       // hidden

typedef __attribute__((ext_vector_type(8))) short bf16x8;
typedef __attribute__((ext_vector_type(4))) float f32x4;
typedef __attribute__((ext_vector_type(4))) float fvec4;
typedef __attribute__((ext_vector_type(4))) unsigned uvec4;

__device__ __forceinline__ unsigned fbits(float f){ union{float f; unsigned u;} v; v.f=f; return v.u; }
__device__ __forceinline__ float ubits(unsigned u){ union{unsigned u; float f;} v; v.u=u; return v.f; }

// pack two f32 -> packed bf16 dword (round-half-up): low short = a
__device__ __forceinline__ unsigned pkf(float a, float b){
  return __builtin_amdgcn_perm(fbits(b)+0x8000u, fbits(a)+0x8000u, 0x07060302u);
}
// packed bf16 pair c * packed bf16 pair d -> packed bf16 products
__device__ __forceinline__ unsigned mulbb(unsigned c, unsigned d){
  float lo = ubits(c << 16) * ubits(d << 16);
  float hi = ubits(c & 0xFFFF0000u) * ubits(d & 0xFFFF0000u);
  return pkf(lo, hi);
}
__device__ __forceinline__ short f2bf_fast(float f){ return (short)((fbits(f)+0x8000u)>>16); }

__device__ __forceinline__ float tanh_fast(float x){
  float t = __builtin_amdgcn_exp2f(x * 2.8853900817779268f);
  return __builtin_fmaf(-2.f, __builtin_amdgcn_rcpf(t + 1.f), 1.f);
}

// Stage W[N=NT*16][K=KT*32] (f32) as bf16 MFMA B-fragments into LDS.
template<int NT, int KT>
__device__ __forceinline__ void stage_w(const float* __restrict__ W, short* lds){
  const int total = NT*KT*64;
  for(int c = (int)threadIdx.x; c < total; c += 256){
    int lane = c & 63;
    int kt = (c >> 6) % KT;
    int n  = c / (64*KT);
    int row = n*16 + (lane & 15);
    int col = kt*32 + (lane >> 4)*8;
    const float* p = W + (size_t)row*(KT*32) + col;
    unsigned* d = (unsigned*)(lds + (size_t)c*8);
#pragma unroll
    for(int j=0;j<4;j++) d[j] = pkf(p[2*j], p[2*j+1]);
  }
}

// ---------------- fused embed + dst histogram ----------------
__global__ void k_prep0(const int* __restrict__ Z, const float* __restrict__ E,
                        float* __restrict__ C, const int* __restrict__ dst, int* __restrict__ cnt){
  int i = blockIdx.x*256 + threadIdx.x;    // exactly NN*32 == NE == 640000
  int node = i >> 5, k4 = i & 31;
  ((float4*)C)[i] = ((const float4*)(E + (size_t)Z[node]*NB))[k4];
  atomicAdd(&cnt[dst[i]], 1);
}

// exclusive scan of cnt -> rp (CSR row pointers, NN+1) and cur (fill cursors)
__global__ __launch_bounds__(1024) void k_scan(const int* __restrict__ cnt,
                                               int* __restrict__ rp, int* __restrict__ cur){
  __shared__ int lds[1024];
  const int t = threadIdx.x;
  const int base = t*20;
  int4 v[5];
#pragma unroll
  for(int j=0;j<5;j++) v[j] = ((const int4*)(cnt + base))[j];
  const int* ve = (const int*)v;
  int loc[20]; int s = 0;
#pragma unroll
  for(int j=0;j<20;j++){ int c = (base+j < NN) ? ve[j] : 0; loc[j] = s; s += c; }
  lds[t] = s;
  __syncthreads();
  for(int off=1; off<1024; off<<=1){
    int x = (t >= off) ? lds[t-off] : 0;
    __syncthreads();
    lds[t] += x;
    __syncthreads();
  }
  int prefix = (t > 0) ? lds[t-1] : 0;
#pragma unroll
  for(int j=0;j<20;j++){
    int i = base+j;
    if(i<NN){ int st = prefix + loc[j]; rp[i] = st; cur[i] = st; }
  }
  if(t == 1023) rp[NN] = NE;
}

__global__ void k_fill(const int* __restrict__ src, const int* __restrict__ dst,
                       int* __restrict__ cur, int* __restrict__ perm, int* __restrict__ srcv){
  int e = blockIdx.x*256 + threadIdx.x;
  if(e < NE){
    int p = atomicAdd(&cur[dst[e]], 1);
    perm[p] = e;
    srcv[p] = src[e];
  }
}

// ---------------- d_feat = edge_attr @ dfW.T + dfb  (bf16, ORIGINAL edge order, streaming) ----------------
#define TPAD 136
__global__ __launch_bounds__(256,3) void k_dprep(
  const float* __restrict__ ea,
  const float* __restrict__ dfW, const float* __restrict__ dfb, short* __restrict__ dft)
{
  __shared__ short ldsW[8*2*64*8];     // 16 KB
  __shared__ short ldsT[4*32*TPAD];    // 34816 B
  stage_w<8,2>(dfW, ldsW);
  __syncthreads();
  const int lane = threadIdx.x & 63, wave = threadIdx.x >> 6;
  const int quad = lane>>4, lc = lane&15;
  short* myT = ldsT + wave*32*TPAD;
  const int wid = blockIdx.x*4 + wave;        // 768*4 = 3072 wids; 20000 tiles of 32 edges
#pragma unroll 1
  for(int tile = wid; tile < NN; tile += 3072){
    const int base = tile*32;
    bf16x8 a[2][2];
#pragma unroll
    for(int mt=0;mt<2;mt++){
      const float* p = ea + (size_t)(base + mt*16 + lc)*NG;   // sequential rows, coalesced
#pragma unroll
      for(int kt=0;kt<2;kt++){
        const float* q = p + kt*32 + quad*8;
        fvec4 c0 = __builtin_nontemporal_load((const fvec4*)q);
        fvec4 c1 = __builtin_nontemporal_load((const fvec4*)(q+4));
        union{ bf16x8 v; unsigned u[4]; } t;
        t.u[0]=pkf(c0.x,c0.y); t.u[1]=pkf(c0.z,c0.w); t.u[2]=pkf(c1.x,c1.y); t.u[3]=pkf(c1.z,c1.w);
        a[mt][kt] = t.v;
      }
    }
    f32x4 acc[2][8];
    f32x4 z = {0.f,0.f,0.f,0.f};
#pragma unroll
    for(int mt=0;mt<2;mt++)
#pragma unroll
      for(int n2=0;n2<8;n2++) acc[mt][n2] = z;
#pragma unroll
    for(int kt=0;kt<2;kt++)
#pragma unroll
      for(int n2=0;n2<8;n2++){
        bf16x8 b = *(const bf16x8*)(ldsW + ((size_t)(n2*2+kt)*64 + lane)*8);
        acc[0][n2] = __builtin_amdgcn_mfma_f32_16x16x32_bf16(a[0][kt], b, acc[0][n2], 0, 0, 0);
        acc[1][n2] = __builtin_amdgcn_mfma_f32_16x16x32_bf16(a[1][kt], b, acc[1][n2], 0, 0, 0);
      }
#pragma unroll
    for(int n2=0;n2<8;n2++){
      float bias = dfb[n2*16 + lc];
#pragma unroll
      for(int mt=0;mt<2;mt++)
#pragma unroll
        for(int r=0;r<4;r++)
          myT[(mt*16 + quad*4 + r)*TPAD + n2*16 + lc] = f2bf_fast(acc[mt][n2][r] + bias);
    }
    short* gout = dft + (size_t)base*NB;
#pragma unroll
    for(int i=0;i<8;i++){
      int s_ = i*512 + lane*8;
      int row = s_ >> 7, col = s_ & 127;
      uvec4 vv = *(const uvec4*)(myT + row*TPAD + col);
      __builtin_nontemporal_store(vv, (uvec4*)(gout + s_));
    }
  }
}

// ---------------- cfC = bf16(C @ cfW.T + cfb) on nodes, LDS-transposed stores ----------------
__global__ __launch_bounds__(256,3) void k_cf(
  const float* __restrict__ C, const float* __restrict__ cfW,
  const float* __restrict__ cfb, short* __restrict__ cfC)
{
  __shared__ short ldsW[8*4*64*8];     // 32 KB
  __shared__ short ldsT[4*16*TPAD];    // 17408 B
  stage_w<8,4>(cfW, ldsW);
  __syncthreads();
  const int lane = threadIdx.x & 63, wave = threadIdx.x >> 6;
  const int quad = lane>>4, lc = lane&15;
  short* myT = ldsT + wave*16*TPAD;
  const int tile = blockIdx.x*4 + wave;       // 313*4 = 1252 >= 1250 tiles
  if(tile >= NN/16) return;
  const int base = tile*16;
  bf16x8 a[4];
  const float* p = C + (size_t)(base + lc)*NB;
#pragma unroll
  for(int kt=0;kt<4;kt++){
    const float* q = p + kt*32 + quad*8;
    float4 c0 = *(const float4*)q, c1 = *(const float4*)(q+4);
    union{ bf16x8 v; unsigned u[4]; } t;
    t.u[0]=pkf(c0.x,c0.y); t.u[1]=pkf(c0.z,c0.w); t.u[2]=pkf(c1.x,c1.y); t.u[3]=pkf(c1.z,c1.w);
    a[kt] = t.v;
  }
  f32x4 acc[8];
  f32x4 z = {0.f,0.f,0.f,0.f};
#pragma unroll
  for(int n2=0;n2<8;n2++) acc[n2] = z;
#pragma unroll
  for(int kt=0;kt<4;kt++)
#pragma unroll
    for(int n2=0;n2<8;n2++){
      bf16x8 b = *(const bf16x8*)(ldsW + ((size_t)(n2*4+kt)*64 + lane)*8);
      acc[n2] = __builtin_amdgcn_mfma_f32_16x16x32_bf16(a[kt], b, acc[n2], 0, 0, 0);
    }
#pragma unroll
  for(int n2=0;n2<8;n2++){
    float bias = cfb[n2*16 + lc];
#pragma unroll
    for(int r=0;r<4;r++)
      myT[(quad*4 + r)*TPAD + n2*16 + lc] = f2bf_fast(acc[n2][r] + bias);
  }
  short* gout = cfC + (size_t)base*NB;
#pragma unroll
  for(int i=0;i<4;i++){
    int s_ = i*512 + lane*8;
    int row = s_ >> 7, col = s_ & 127;
    uint4 vv = *(const uint4*)(myT + row*TPAD + col);
    *(uint4*)(gout + s_) = vv;
  }
}

// ---------------- edge kernel: one WAVE per node, no atomics ----------------
// C[v] += sum_{edges j of v} tanh((cfC[srcv[j]] * dft[perm[j]]) @ fcW.T)
__global__ __launch_bounds__(256,4) void k_edge(
    const short* __restrict__ cfC, const short* __restrict__ dft,
    const int* __restrict__ perm, const int* __restrict__ srcv,
    const int* __restrict__ rp,
    const float* __restrict__ fcW, float* __restrict__ C)
{
  __shared__ short ldsW[8*4*64*8];   // 32 KB
  stage_w<8,4>(fcW, ldsW);
  __syncthreads();
  const int lane = threadIdx.x & 63, wave = threadIdx.x >> 6;
  const int quad = lane>>4, lc = lane&15;
  const int wid = blockIdx.x*4 + wave;      // 1024*4 = 4096 waves
#pragma unroll 1
  for(int v = wid; v < NN; v += 4096){
    const int j0 = rp[v], j1 = rp[v+1];
    if(j0 >= j1) continue;
    float nsum[8];
#pragma unroll
    for(int n2=0;n2<8;n2++) nsum[n2] = 0.f;
#pragma unroll 1
    for(int t0 = j0; t0 < j1; t0 += 16){
      int j = t0 + lc; if(j > j1-1) j = j1-1;       // clamp, mask later
      const short* cp = cfC + (size_t)srcv[j]*NB;
      const short* dp = dft + (size_t)perm[j]*NB;
      bf16x8 a2[4];
#pragma unroll
      for(int kt=0; kt<4; kt++){
        uint4 cc = *(const uint4*)(cp + kt*32 + quad*8);
        uvec4 dd = __builtin_nontemporal_load((const uvec4*)(dp + kt*32 + quad*8));
        union{ bf16x8 v; unsigned u[4]; } t;
        t.u[0] = mulbb(cc.x, dd.x);
        t.u[1] = mulbb(cc.y, dd.y);
        t.u[2] = mulbb(cc.z, dd.z);
        t.u[3] = mulbb(cc.w, dd.w);
        a2[kt] = t.v;
      }
      f32x4 acc[8];
      f32x4 z = {0.f,0.f,0.f,0.f};
#pragma unroll
      for(int n2=0;n2<8;n2++) acc[n2] = z;
#pragma unroll
      for(int kt=0; kt<4; kt++)
#pragma unroll
        for(int n2=0; n2<8; n2++){
          bf16x8 b = *(const bf16x8*)(ldsW + ((size_t)(n2*4 + kt)*64 + lane)*8);
          acc[n2] = __builtin_amdgcn_mfma_f32_16x16x32_bf16(a2[kt], b, acc[n2], 0, 0, 0);
        }
      // tanh + masked row-sum (rows = edges t0+quad*4+r; col = n2*16+lc)
#pragma unroll
      for(int r=0; r<4; r++){
        float sel = (t0 + quad*4 + r < j1) ? 1.f : 0.f;
#pragma unroll
        for(int n2=0;n2<8;n2++)
          nsum[n2] = __builtin_fmaf(tanh_fast(acc[n2][r]), sel, nsum[n2]);
      }
    }
    // reduce across quads (rows) -> every lane has full column sums
#pragma unroll
    for(int n2=0;n2<8;n2++){
      nsum[n2] += __shfl_xor(nsum[n2], 16);
      nsum[n2] += __shfl_xor(nsum[n2], 32);
    }
    // single-owner RMW, quad-distributed: quad q writes cols n2 = 2q, 2q+1
    float* cv = C + (size_t)v*NB;
    const int n2w = quad*2;
    cv[n2w*16 + lc]     += nsum[n2w];
    cv[(n2w+1)*16 + lc] += nsum[n2w+1];
  }
}

// ---------------- readout: out += pool(tanh(C@r1W.T + r1b)@r2W.T + r2b) ----------------
__global__ __launch_bounds__(256,2) void k_readout(
  const float* __restrict__ C, const float* __restrict__ r1W, const float* __restrict__ r1b,
  const float* __restrict__ r2W, const float* __restrict__ r2b,
  const int* __restrict__ batch, float* __restrict__ out)
{
  __shared__ short ldsW[16*4*64*8];  // 64 KB
  stage_w<16,4>(r1W, ldsW);
  __syncthreads();
  const int lane = threadIdx.x & 63, wave = threadIdx.x >> 6;
  const int quad = lane>>4, lc = lane&15;
  const int base = (blockIdx.x*4 + wave)*16;
  if(base >= NN) return;
  int node = base + lc; if(node > NN-1) node = NN-1;
  bf16x8 a[4];
  const float* p = C + (size_t)node*NB;
#pragma unroll
  for(int kt=0;kt<4;kt++){
    const float* q = p + kt*32 + quad*8;
    float4 c0 = *(const float4*)q, c1 = *(const float4*)(q+4);
    union{ bf16x8 v; unsigned u[4]; } t;
    t.u[0]=pkf(c0.x,c0.y); t.u[1]=pkf(c0.z,c0.w); t.u[2]=pkf(c1.x,c1.y); t.u[3]=pkf(c1.z,c1.w);
    a[kt] = t.v;
  }
  f32x4 acc[16];
  f32x4 z = {0.f,0.f,0.f,0.f};
#pragma unroll
  for(int nt=0;nt<16;nt++) acc[nt] = z;
#pragma unroll
  for(int kt=0;kt<4;kt++)
#pragma unroll
    for(int nt=0;nt<16;nt++){
      bf16x8 b = *(const bf16x8*)(ldsW + ((size_t)(nt*4+kt)*64 + lane)*8);
      acc[nt] = __builtin_amdgcn_mfma_f32_16x16x32_bf16(a[kt], b, acc[nt], 0, 0, 0);
    }
#pragma unroll
  for(int nt=0;nt<16;nt++){
    float bias = r1b[nt*16 + lc];
#pragma unroll
    for(int r=0;r<4;r++) acc[nt][r] = tanh_fast(acc[nt][r] + bias);
  }
#pragma unroll
  for(int r=0;r<4;r++){
    int nd = base + quad*4 + r;
#pragma unroll
    for(int o=0;o<4;o++){
      float ps = 0.f;
#pragma unroll
      for(int nt=0;nt<16;nt++) ps = __builtin_fmaf(acc[nt][r], r2W[(size_t)o*NH + nt*16 + lc], ps);
      ps += __shfl_xor(ps, 1);
      ps += __shfl_xor(ps, 2);
      ps += __shfl_xor(ps, 4);
      ps += __shfl_xor(ps, 8);
      if(lc == 0 && nd < NN) atomicAdd(&out[batch[nd]*4 + o], ps + r2b[o]);
    }
  }
}

extern "C" void kernel_launch(void* const* d_in, const int* in_sizes, int n_in,
                              void* d_out, int out_size, void* d_ws, size_t ws_size,
                              hipStream_t stream) {
  const int*   Z      = (const int*)d_in[0];
  const int*   ei     = (const int*)d_in[1];
  const float* ea     = (const float*)d_in[2];
  const int*   batch  = (const int*)d_in[3];
  const float* embedW = (const float*)d_in[4];
  const float* cfW    = (const float*)d_in[5];
  const float* cfb    = (const float*)d_in[6];
  const float* dfW    = (const float*)d_in[7];
  const float* dfb    = (const float*)d_in[8];
  const float* fcW    = (const float*)d_in[9];
  const float* r1W    = (const float*)d_in[10];
  const float* r1b    = (const float*)d_in[11];
  const float* r2W    = (const float*)d_in[12];
  const float* r2b    = (const float*)d_in[13];
  const int* src = ei;
  const int* dst = ei + NE;

  char* p = (char*)d_ws;
  auto alloc = [&](size_t b){ char* r = p; p += (b + 255) & ~(size_t)255; return r; };
  float* CA    = (float*)alloc((size_t)NN*NB*4);
  short* cfC   = (short*)alloc((size_t)NN*NB*2);
  short* dft   = (short*)alloc((size_t)NE*NB*2);
  int*   cnt   = (int*)alloc((size_t)NN*4);
  int*   rp    = (int*)alloc((size_t)(NN+1)*4);
  int*   cursor= (int*)alloc((size_t)NN*4);
  int*   perm  = (int*)alloc((size_t)NE*4);
  int*   srcv  = (int*)alloc((size_t)NE*4);
  size_t needed = (size_t)(p - (char*)d_ws);

  (void)hipMemsetAsync(d_out, 0, (size_t)out_size*sizeof(float), stream);
  if(needed > ws_size) return;   // all-zero output = ws-too-small diagnostic

  (void)hipMemsetAsync(cnt, 0, (size_t)NN*4, stream);
  k_prep0<<<2500, 256, 0, stream>>>(Z, embedW, CA, dst, cnt);
  k_scan <<<1,   1024, 0, stream>>>(cnt, rp, cursor);
  k_fill <<<2500, 256, 0, stream>>>(src, dst, cursor, perm, srcv);
  k_dprep<<<768,  256, 0, stream>>>(ea, dfW, dfb, dft);

  for(int it = 0; it < 3; it++){
    k_cf  <<<313,  256, 0, stream>>>(CA, cfW, cfb, cfC);
    k_edge<<<1024, 256, 0, stream>>>(cfC, dft, perm, srcv, rp, fcW, CA);
  }
  k_readout<<<313, 256, 0, stream>>>(CA, r1W, r1b, r2W, r2b, batch, (float*)d_out);
}

// Round 6
// 714.847 us; speedup vs baseline: 1.8517x; 1.8517x over previous
//
#include <hip/hip_runtime.h>
#include <cstdint>

#define NN 20000     // nodes
#define NE 640000    // edges
#define NB 128       // basis
#define NG 64        // gaussians
#define NH 256       // hidden

typedef __attribute__((ext_vector_type(8))) short bf16x8;
typedef __attribute__((ext_vector_type(4))) float f32x4;
typedef __attribute__((ext_vector_type(4))) float fvec4;
typedef __attribute__((ext_vector_type(4))) unsigned uvec4;

__device__ __forceinline__ unsigned fbits(float f){ union{float f; unsigned u;} v; v.f=f; return v.u; }
__device__ __forceinline__ float ubits(unsigned u){ union{unsigned u; float f;} v; v.u=u; return v.f; }

// pack two f32 -> packed bf16 dword (round-half-up): low short = a
__device__ __forceinline__ unsigned pkf(float a, float b){
  return __builtin_amdgcn_perm(fbits(b)+0x8000u, fbits(a)+0x8000u, 0x07060302u);
}
// packed bf16 pair c * packed bf16 pair d -> packed bf16 products
__device__ __forceinline__ unsigned mulbb(unsigned c, unsigned d){
  float lo = ubits(c << 16) * ubits(d << 16);
  float hi = ubits(c & 0xFFFF0000u) * ubits(d & 0xFFFF0000u);
  return pkf(lo, hi);
}
__device__ __forceinline__ short f2bf_fast(float f){ return (short)((fbits(f)+0x8000u)>>16); }

__device__ __forceinline__ float tanh_fast(float x){
  float t = __builtin_amdgcn_exp2f(x * 2.8853900817779268f);
  return __builtin_fmaf(-2.f, __builtin_amdgcn_rcpf(t + 1.f), 1.f);
}

// Stage W[N=NT*16][K=KT*32] (f32) as bf16 MFMA B-fragments into LDS.
template<int NT, int KT>
__device__ __forceinline__ void stage_w(const float* __restrict__ W, short* lds){
  const int total = NT*KT*64;
  for(int c = (int)threadIdx.x; c < total; c += 256){
    int lane = c & 63;
    int kt = (c >> 6) % KT;
    int n  = c / (64*KT);
    int row = n*16 + (lane & 15);
    int col = kt*32 + (lane >> 4)*8;
    const float* p = W + (size_t)row*(KT*32) + col;
    unsigned* d = (unsigned*)(lds + (size_t)c*8);
#pragma unroll
    for(int j=0;j<4;j++) d[j] = pkf(p[2*j], p[2*j+1]);
  }
}

// ---------------- fused embed + dst histogram ----------------
__global__ void k_prep0(const int* __restrict__ Z, const float* __restrict__ E,
                        float* __restrict__ C, const int* __restrict__ dst, int* __restrict__ cnt){
  int i = blockIdx.x*256 + threadIdx.x;    // exactly NN*32 == NE == 640000
  int node = i >> 5, k4 = i & 31;
  ((float4*)C)[i] = ((const float4*)(E + (size_t)Z[node]*NB))[k4];
  atomicAdd(&cnt[dst[i]], 1);
}

__global__ __launch_bounds__(1024) void k_scan(const int* __restrict__ cnt, int* __restrict__ cur){
  __shared__ int lds[1024];
  const int t = threadIdx.x;
  const int base = t*20;
  int4 v[5];
#pragma unroll
  for(int j=0;j<5;j++) v[j] = ((const int4*)(cnt + base))[j];
  const int* ve = (const int*)v;
  int loc[20]; int s = 0;
#pragma unroll
  for(int j=0;j<20;j++){ int c = (base+j < NN) ? ve[j] : 0; loc[j] = s; s += c; }
  lds[t] = s;
  __syncthreads();
  for(int off=1; off<1024; off<<=1){
    int x = (t >= off) ? lds[t-off] : 0;
    __syncthreads();
    lds[t] += x;
    __syncthreads();
  }
  int prefix = (t > 0) ? lds[t-1] : 0;
#pragma unroll
  for(int j=0;j<20;j++){ int i = base+j; if(i<NN) cur[i] = prefix + loc[j]; }
}

__global__ void k_fill(const int* __restrict__ src, const int* __restrict__ dst,
                       int* __restrict__ cur, int* __restrict__ perm,
                       int* __restrict__ srcv, int* __restrict__ dstv){
  int e = blockIdx.x*256 + threadIdx.x;
  if(e < NE){
    int v = dst[e];
    int p = atomicAdd(&cur[v], 1);
    perm[p] = e;
    srcv[p] = src[e];
    dstv[p] = v;
  }
}

// ---------------- d_feat = edge_attr[perm] @ dfW.T + dfb  (bf16, perm order, LDS-transposed stores) ----------------
#define TPAD 136
__global__ __launch_bounds__(256,3) void k_dprep(
  const float* __restrict__ ea, const int* __restrict__ perm,
  const float* __restrict__ dfW, const float* __restrict__ dfb, short* __restrict__ dft)
{
  __shared__ short ldsW[8*2*64*8];     // 16 KB
  __shared__ short ldsT[4*32*TPAD];    // 34816 B
  stage_w<8,2>(dfW, ldsW);
  __syncthreads();
  const int lane = threadIdx.x & 63, wave = threadIdx.x >> 6;
  const int quad = lane>>4, lc = lane&15;
  short* myT = ldsT + wave*32*TPAD;
  const int wid = blockIdx.x*4 + wave;        // 768*4 = 3072 wids; 20000 tiles of 32 edges
#pragma unroll 1
  for(int tile = wid; tile < NN; tile += 3072){
    const int base = tile*32;
    bf16x8 a[2][2];
#pragma unroll
    for(int mt=0;mt<2;mt++){
      int e = perm[base + mt*16 + lc];
      const float* p = ea + (size_t)e*NG;
#pragma unroll
      for(int kt=0;kt<2;kt++){
        const float* q = p + kt*32 + quad*8;
        fvec4 c0 = __builtin_nontemporal_load((const fvec4*)q);
        fvec4 c1 = __builtin_nontemporal_load((const fvec4*)(q+4));
        union{ bf16x8 v; unsigned u[4]; } t;
        t.u[0]=pkf(c0.x,c0.y); t.u[1]=pkf(c0.z,c0.w); t.u[2]=pkf(c1.x,c1.y); t.u[3]=pkf(c1.z,c1.w);
        a[mt][kt] = t.v;
      }
    }
    f32x4 acc[2][8];
    f32x4 z = {0.f,0.f,0.f,0.f};
#pragma unroll
    for(int mt=0;mt<2;mt++)
#pragma unroll
      for(int n2=0;n2<8;n2++) acc[mt][n2] = z;
#pragma unroll
    for(int kt=0;kt<2;kt++)
#pragma unroll
      for(int n2=0;n2<8;n2++){
        bf16x8 b = *(const bf16x8*)(ldsW + ((size_t)(n2*2+kt)*64 + lane)*8);
        acc[0][n2] = __builtin_amdgcn_mfma_f32_16x16x32_bf16(a[0][kt], b, acc[0][n2], 0, 0, 0);
        acc[1][n2] = __builtin_amdgcn_mfma_f32_16x16x32_bf16(a[1][kt], b, acc[1][n2], 0, 0, 0);
      }
#pragma unroll
    for(int n2=0;n2<8;n2++){
      float bias = dfb[n2*16 + lc];
#pragma unroll
      for(int mt=0;mt<2;mt++)
#pragma unroll
        for(int r=0;r<4;r++)
          myT[(mt*16 + quad*4 + r)*TPAD + n2*16 + lc] = f2bf_fast(acc[mt][n2][r] + bias);
    }
    short* gout = dft + (size_t)base*NB;
#pragma unroll
    for(int i=0;i<8;i++){
      int s_ = i*512 + lane*8;
      int row = s_ >> 7, col = s_ & 127;
      uvec4 vv = *(const uvec4*)(myT + row*TPAD + col);
      __builtin_nontemporal_store(vv, (uvec4*)(gout + s_));
    }
  }
}

// ---------------- cfC = bf16(C @ cfW.T + cfb) on nodes, LDS-transposed stores ----------------
__global__ __launch_bounds__(256,3) void k_cf(
  const float* __restrict__ C, const float* __restrict__ cfW,
  const float* __restrict__ cfb, short* __restrict__ cfC)
{
  __shared__ short ldsW[8*4*64*8];     // 32 KB
  __shared__ short ldsT[4*16*TPAD];    // 17408 B
  stage_w<8,4>(cfW, ldsW);
  __syncthreads();
  const int lane = threadIdx.x & 63, wave = threadIdx.x >> 6;
  const int quad = lane>>4, lc = lane&15;
  short* myT = ldsT + wave*16*TPAD;
  const int tile = blockIdx.x*4 + wave;       // 313*4 = 1252 >= 1250 tiles
  if(tile >= NN/16) return;
  const int base = tile*16;
  bf16x8 a[4];
  const float* p = C + (size_t)(base + lc)*NB;
#pragma unroll
  for(int kt=0;kt<4;kt++){
    const float* q = p + kt*32 + quad*8;
    float4 c0 = *(const float4*)q, c1 = *(const float4*)(q+4);
    union{ bf16x8 v; unsigned u[4]; } t;
    t.u[0]=pkf(c0.x,c0.y); t.u[1]=pkf(c0.z,c0.w); t.u[2]=pkf(c1.x,c1.y); t.u[3]=pkf(c1.z,c1.w);
    a[kt] = t.v;
  }
  f32x4 acc[8];
  f32x4 z = {0.f,0.f,0.f,0.f};
#pragma unroll
  for(int n2=0;n2<8;n2++) acc[n2] = z;
#pragma unroll
  for(int kt=0;kt<4;kt++)
#pragma unroll
    for(int n2=0;n2<8;n2++){
      bf16x8 b = *(const bf16x8*)(ldsW + ((size_t)(n2*4+kt)*64 + lane)*8);
      acc[n2] = __builtin_amdgcn_mfma_f32_16x16x32_bf16(a[kt], b, acc[n2], 0, 0, 0);
    }
#pragma unroll
  for(int n2=0;n2<8;n2++){
    float bias = cfb[n2*16 + lc];
#pragma unroll
    for(int r=0;r<4;r++)
      myT[(quad*4 + r)*TPAD + n2*16 + lc] = f2bf_fast(acc[n2][r] + bias);
  }
  short* gout = cfC + (size_t)base*NB;
#pragma unroll
  for(int i=0;i<4;i++){
    int s_ = i*512 + lane*8;
    int row = s_ >> 7, col = s_ & 127;
    uint4 vv = *(const uint4*)(myT + row*TPAD + col);
    *(uint4*)(gout + s_) = vv;
  }
}

// ---------------- edge kernel: round-1 memory structure + mulbb VALU diet ----------------
// C += scatter(tanh((cfC[src] * dft) @ fcW.T)), edges dst-sorted, atomics per segment
__global__ __launch_bounds__(256,2) void k_edge(
    const short* __restrict__ cfC, const short* __restrict__ dft,
    const int* __restrict__ srcv, const int* __restrict__ dstv,
    const float* __restrict__ fcW, float* __restrict__ C)
{
  __shared__ short ldsW[8*4*64*8];   // 32 KB
  stage_w<8,4>(fcW, ldsW);
  __syncthreads();
  const int lane = threadIdx.x & 63, wave = threadIdx.x >> 6;
  const int quad = lane>>4, lc = lane&15;
  const int tile0 = (blockIdx.x*4 + wave)*2;   // 2500 blocks * 4 waves * 2 tiles * 32 edges = NE
#pragma unroll 1
  for(int s = 0; s < 2; s++){
    const int base = (tile0 + s)*32;
    bf16x8 a2[2][4];
#pragma unroll
    for(int mt=0; mt<2; mt++){
      const int e = base + mt*16 + lc;
      const short* cp = cfC + (size_t)srcv[e]*NB;
      const short* dp = dft + (size_t)e*NB;
#pragma unroll
      for(int kt=0; kt<4; kt++){
        uint4 cc = *(const uint4*)(cp + kt*32 + quad*8);
        uint4 dd = *(const uint4*)(dp + kt*32 + quad*8);
        union{ bf16x8 v; unsigned u[4]; } t;
        t.u[0] = mulbb(cc.x, dd.x);
        t.u[1] = mulbb(cc.y, dd.y);
        t.u[2] = mulbb(cc.z, dd.z);
        t.u[3] = mulbb(cc.w, dd.w);
        a2[mt][kt] = t.v;
      }
    }
    f32x4 acc[2][8];
    f32x4 z = {0.f,0.f,0.f,0.f};
#pragma unroll
    for(int mt=0;mt<2;mt++)
#pragma unroll
      for(int n2=0;n2<8;n2++) acc[mt][n2] = z;
#pragma unroll
    for(int kt=0; kt<4; kt++)
#pragma unroll
      for(int n2=0; n2<8; n2++){
        bf16x8 b = *(const bf16x8*)(ldsW + ((size_t)(n2*4 + kt)*64 + lane)*8);
        acc[0][n2] = __builtin_amdgcn_mfma_f32_16x16x32_bf16(a2[0][kt], b, acc[0][n2], 0, 0, 0);
        acc[1][n2] = __builtin_amdgcn_mfma_f32_16x16x32_bf16(a2[1][kt], b, acc[1][n2], 0, 0, 0);
      }
#pragma unroll
    for(int mt=0;mt<2;mt++)
#pragma unroll
      for(int n2=0;n2<8;n2++)
#pragma unroll
        for(int r=0;r<4;r++) acc[mt][n2][r] = tanh_fast(acc[mt][n2][r]);

    // segmented reduction over dst (perm-sorted) + quad-distributed atomics
    const int i = lane & 31;
    const int di = dstv[base + i];
    const int dprev = (i > 0) ? dstv[base + i - 1] : -1;
    unsigned long long mm = __ballot(di != dprev) & 0xFFFFFFFFull;
    while(mm){
      int lo = __ffsll(mm) - 1;
      mm &= mm - 1;
      int hi = mm ? (__ffsll(mm) - 1) : 32;
      int v = __shfl(di, lo);
      float sums[8];
#pragma unroll
      for(int n2=0;n2<8;n2++) sums[n2] = 0.f;
#pragma unroll
      for(int mt=0; mt<2; mt++)
#pragma unroll
        for(int r=0; r<4; r++){
          int e2 = mt*16 + quad*4 + r;
          float sel = (e2 >= lo && e2 < hi) ? 1.f : 0.f;
#pragma unroll
          for(int n2=0;n2<8;n2++) sums[n2] = __builtin_fmaf(acc[mt][n2][r], sel, sums[n2]);
        }
#pragma unroll
      for(int n2=0;n2<8;n2++){
        sums[n2] += __shfl_xor(sums[n2], 16);
        sums[n2] += __shfl_xor(sums[n2], 32);
      }
      const int n2w = quad*2;
      atomicAdd(&C[(size_t)v*NB + n2w*16 + lc],     sums[n2w]);
      atomicAdd(&C[(size_t)v*NB + (n2w+1)*16 + lc], sums[n2w+1]);
    }
  }
}

// ---------------- readout: out += pool(tanh(C@r1W.T + r1b)@r2W.T + r2b) ----------------
__global__ __launch_bounds__(256,2) void k_readout(
  const float* __restrict__ C, const float* __restrict__ r1W, const float* __restrict__ r1b,
  const float* __restrict__ r2W, const float* __restrict__ r2b,
  const int* __restrict__ batch, float* __restrict__ out)
{
  __shared__ short ldsW[16*4*64*8];  // 64 KB
  stage_w<16,4>(r1W, ldsW);
  __syncthreads();
  const int lane = threadIdx.x & 63, wave = threadIdx.x >> 6;
  const int quad = lane>>4, lc = lane&15;
  const int base = (blockIdx.x*4 + wave)*16;
  if(base >= NN) return;
  int node = base + lc; if(node > NN-1) node = NN-1;
  bf16x8 a[4];
  const float* p = C + (size_t)node*NB;
#pragma unroll
  for(int kt=0;kt<4;kt++){
    const float* q = p + kt*32 + quad*8;
    float4 c0 = *(const float4*)q, c1 = *(const float4*)(q+4);
    union{ bf16x8 v; unsigned u[4]; } t;
    t.u[0]=pkf(c0.x,c0.y); t.u[1]=pkf(c0.z,c0.w); t.u[2]=pkf(c1.x,c1.y); t.u[3]=pkf(c1.z,c1.w);
    a[kt] = t.v;
  }
  f32x4 acc[16];
  f32x4 z = {0.f,0.f,0.f,0.f};
#pragma unroll
  for(int nt=0;nt<16;nt++) acc[nt] = z;
#pragma unroll
  for(int kt=0;kt<4;kt++)
#pragma unroll
    for(int nt=0;nt<16;nt++){
      bf16x8 b = *(const bf16x8*)(ldsW + ((size_t)(nt*4+kt)*64 + lane)*8);
      acc[nt] = __builtin_amdgcn_mfma_f32_16x16x32_bf16(a[kt], b, acc[nt], 0, 0, 0);
    }
#pragma unroll
  for(int nt=0;nt<16;nt++){
    float bias = r1b[nt*16 + lc];
#pragma unroll
    for(int r=0;r<4;r++) acc[nt][r] = tanh_fast(acc[nt][r] + bias);
  }
#pragma unroll
  for(int r=0;r<4;r++){
    int nd = base + quad*4 + r;
#pragma unroll
    for(int o=0;o<4;o++){
      float ps = 0.f;
#pragma unroll
      for(int nt=0;nt<16;nt++) ps = __builtin_fmaf(acc[nt][r], r2W[(size_t)o*NH + nt*16 + lc], ps);
      ps += __shfl_xor(ps, 1);
      ps += __shfl_xor(ps, 2);
      ps += __shfl_xor(ps, 4);
      ps += __shfl_xor(ps, 8);
      if(lc == 0 && nd < NN) atomicAdd(&out[batch[nd]*4 + o], ps + r2b[o]);
    }
  }
}

extern "C" void kernel_launch(void* const* d_in, const int* in_sizes, int n_in,
                              void* d_out, int out_size, void* d_ws, size_t ws_size,
                              hipStream_t stream) {
  const int*   Z      = (const int*)d_in[0];
  const int*   ei     = (const int*)d_in[1];
  const float* ea     = (const float*)d_in[2];
  const int*   batch  = (const int*)d_in[3];
  const float* embedW = (const float*)d_in[4];
  const float* cfW    = (const float*)d_in[5];
  const float* cfb    = (const float*)d_in[6];
  const float* dfW    = (const float*)d_in[7];
  const float* dfb    = (const float*)d_in[8];
  const float* fcW    = (const float*)d_in[9];
  const float* r1W    = (const float*)d_in[10];
  const float* r1b    = (const float*)d_in[11];
  const float* r2W    = (const float*)d_in[12];
  const float* r2b    = (const float*)d_in[13];
  const int* src = ei;
  const int* dst = ei + NE;

  char* p = (char*)d_ws;
  auto alloc = [&](size_t b){ char* r = p; p += (b + 255) & ~(size_t)255; return r; };
  float* CA    = (float*)alloc((size_t)NN*NB*4);
  short* cfC   = (short*)alloc((size_t)NN*NB*2);
  short* dft   = (short*)alloc((size_t)NE*NB*2);
  int*   cnt   = (int*)alloc((size_t)NN*4);
  int*   cursor= (int*)alloc((size_t)NN*4);
  int*   perm  = (int*)alloc((size_t)NE*4);
  int*   srcv  = (int*)alloc((size_t)NE*4);
  int*   dstv  = (int*)alloc((size_t)NE*4);
  size_t needed = (size_t)(p - (char*)d_ws);

  (void)hipMemsetAsync(d_out, 0, (size_t)out_size*sizeof(float), stream);
  if(needed > ws_size) return;   // all-zero output = ws-too-small diagnostic

  (void)hipMemsetAsync(cnt, 0, (size_t)NN*4, stream);
  k_prep0<<<2500, 256, 0, stream>>>(Z, embedW, CA, dst, cnt);
  k_scan <<<1,   1024, 0, stream>>>(cnt, cursor);
  k_fill <<<2500, 256, 0, stream>>>(src, dst, cursor, perm, srcv, dstv);
  k_dprep<<<768,  256, 0, stream>>>(ea, perm, dfW, dfb, dft);

  for(int it = 0; it < 3; it++){
    k_cf  <<<313,  256, 0, stream>>>(CA, cfW, cfb, cfC);
    k_edge<<<2500, 256, 0, stream>>>(cfC, dft, srcv, dstv, fcW, CA);
  }
  k_readout<<<313, 256, 0, stream>>>(CA, r1W, r1b, r2W, r2b, batch, (float*)d_out);
}